// Round 15
// baseline (577.217 us; speedup 1.0000x reference)
//
#include <hip/hip_runtime.h>

#define HD 50
#define TT 512
#define BRR 8         // batch rows per block -> 512 blocks = 2 per CU (stall-filling pairs)
#define TC 32         // x prefetch chunk (timesteps)
#define KS 136        // shorts per A row (272B): [0..49]=h0 | [50..52]=x | 53..63=0 | [64..113]=h1 | 114..135=0

using f16   = _Float16;
using f16x8 = __attribute__((ext_vector_type(8))) f16;
using f32x4 = __attribute__((ext_vector_type(4))) float;

#define LOG2E 1.4426950408889634f

__device__ __forceinline__ short f2h_bits(float f) {
    f16 h = (f16)f;                      // RNE
    return *reinterpret_cast<short*>(&h);
}
__device__ __forceinline__ float h2f(short b) {
    f16 h = *reinterpret_cast<f16*>(&b);
    return (float)h;
}
__device__ __forceinline__ float frcp(float x) { return __builtin_amdgcn_rcpf(x); }
#if __has_builtin(__builtin_amdgcn_exp2f)
__device__ __forceinline__ float fexp2(float x) { return __builtin_amdgcn_exp2f(x); }
#else
__device__ __forceinline__ float fexp2(float x) { return exp2f(x); }
#endif

// 256-thread blocks, BRR=8 rows, grid=512 -> TWO independent blocks per CU.
// Their barriers drift anti-phase, so one block's EW (VALU/trans) fills the
// other's MFMA/read/barrier stalls (m114 co-scheduling across waves).
// Each wave w owns units u = 4*lr + w for BOTH layers:
//   set A = L0 gates (k chunks 0,1 -> 8 MFMA), set B = L1 gates (chunks 0..3 -> 16 MFMA).
// BRR=8 leaves D rows 8-15 garbage (A rows 8-15 stay zero); EW is compacted via
// __shfl_xor(32): upper half-wave processes the lower half's j=2,3 accs, so all
// 64 lanes do 2 updates per set (trans issue not doubled by divergence).
// One barrier per tick; A double-buffered; same EW math as r13 (absmax must stay
// exactly 4.882812e-4 - any change means a mapping bug).
__global__ __launch_bounds__(256, 2) void lstm2_dual(
    const float* __restrict__ x,
    const float* __restrict__ Wih0, const float* __restrict__ Whh0,
    const float* __restrict__ bih0, const float* __restrict__ bhh0,
    const float* __restrict__ Wih1, const float* __restrict__ Whh1,
    const float* __restrict__ bih1, const float* __restrict__ bhh1,
    const float* __restrict__ Wfc, const float* __restrict__ bfc,
    float* __restrict__ out)
{
    __shared__ short s_A[2][16][KS];          // rows 8-15 permanently zero
    __shared__ float s_xs[2][BRR][TC * 3];

    const int tid  = threadIdx.x;
    const int wid  = tid >> 6;                // 0..3
    const int lane = tid & 63;
    const int lr   = lane & 15;               // B/D column = unit slot
    const int lq   = lane >> 4;               // k-octet / D row-quad
    const int r0   = blockIdx.x * BRR;

    const int  u     = 4 * lr + wid;          // this lane's unit (both layers)
    const bool valid = (u < HD);
    const bool hi    = (lane >= 32);
    const int  rwb   = (lq & 1) * 4 + ((lq >> 1) & 1) * 2;  // lane's 2-row base (0,2,4,6)

    // ---- weight fragments (f16, pre-scaled), register-resident ----
    f16x8 bwA[4][2], bwB[4][4];
    float bvA[4], bvB[4];
    #pragma unroll
    for (int tt = 0; tt < 4; ++tt) {
        const float sc = (tt == 2) ? (2.0f * LOG2E) : (-LOG2E);
        const int g = tt * HD + (valid ? u : 0);
        bvA[tt] = valid ? (bih0[g] + bhh0[g]) * sc : 0.f;
        #pragma unroll
        for (int s = 0; s < 2; ++s) {
            #pragma unroll
            for (int j = 0; j < 8; ++j) {
                const int k = s * 32 + lq * 8 + j;
                float wv = 0.f;
                if (valid) {
                    if (k < HD) wv = Whh0[g * HD + k];
                    else if (k < HD + 3) wv = Wih0[g * 3 + (k - HD)];
                }
                bwA[tt][s][j] = (f16)(wv * sc);
            }
        }
        bvB[tt] = valid ? (bih1[g] + bhh1[g]) * sc : 0.f;
        #pragma unroll
        for (int s = 0; s < 4; ++s) {
            #pragma unroll
            for (int j = 0; j < 8; ++j) {
                const int k = s * 32 + lq * 8 + j;
                float wv = 0.f;
                if (valid) {
                    if (k < HD) wv = Wih1[g * HD + k];
                    else if (k >= 64 && k < 64 + HD) wv = Whh1[g * HD + (k - 64)];
                }
                bwB[tt][s][j] = (f16)(wv * sc);
            }
        }
    }

    // ---- per-lane c-state: 2 rows per set ----
    float cstA[2] = {0.f, 0.f};
    float cstB[2] = {0.f, 0.f};

    // ---- x duty: wave 0, lr 13..15 (12 fully-invalid lanes) x 2 slots = 24 writes ----
    const bool xduty = (wid == 0) && (lr >= 13);
    const int  xi    = (lr - 13) * 4 + lq;    // 0..11

    // ---- init: zero A (incl. rows 8-15), stage x chunk 0, write x(0) ----
    for (int q = tid; q < 2 * 16 * KS; q += 256) ((short*)s_A)[q] = 0;
    for (int q = tid; q < BRR * TC * 3; q += 256) {
        const int rr = q / (TC * 3), qq = q % (TC * 3);
        s_xs[0][rr][qq] = x[(size_t)(r0 + rr) * (TT * 3) + qq];
    }
    __syncthreads();
    if (xduty) {
        #pragma unroll
        for (int e = 0; e < 2; ++e) {
            const int slot = 2 * xi + e;      // 0..23
            const int rr = slot / 3, dd = slot % 3;
            s_A[0][rr][HD + dd] = f2h_bits(s_xs[0][rr][dd]);
        }
    }
    __syncthreads();

    // ================= main loop: TT+1 ticks, ONE barrier each =================
    for (int n = 0; n <= TT; ++n) {
        // ---- A fragments (chunks 0..3; A uses 0,1; B uses 0..3) ----
        const char* ab = (const char*)&s_A[n & 1][0][0];
        f16x8 a[4];
        #pragma unroll
        for (int s = 0; s < 4; ++s)
            a[s] = *(const f16x8*)(ab + lr * (2 * KS) + s * 64 + lq * 16);

        // ---- MFMA: set A (L0, 8) + set B (L1, 16) ----
        f32x4 accA[4], accB[4];
        #pragma unroll
        for (int tt = 0; tt < 4; ++tt) { const float b = bvA[tt]; accA[tt] = (f32x4){b, b, b, b}; }
        #pragma unroll
        for (int tt = 0; tt < 4; ++tt) { const float b = bvB[tt]; accB[tt] = (f32x4){b, b, b, b}; }
        #pragma unroll
        for (int s = 0; s < 2; ++s) {
            #pragma unroll
            for (int tt = 0; tt < 4; ++tt)
                accA[tt] = __builtin_amdgcn_mfma_f32_16x16x32_f16(a[s], bwA[tt][s], accA[tt], 0, 0, 0);
        }
        #pragma unroll
        for (int s = 0; s < 4; ++s) {
            #pragma unroll
            for (int tt = 0; tt < 4; ++tt)
                accB[tt] = __builtin_amdgcn_mfma_f32_16x16x32_f16(a[s], bwB[tt][s], accB[tt], 0, 0, 0);
        }

        // ---- compaction: upper half-wave takes lower half's j=2,3 ----
        float swA[4][2], swB[4][2];
        #pragma unroll
        for (int tt = 0; tt < 4; ++tt) {
            #pragma unroll
            for (int jj = 0; jj < 2; ++jj) {
                swA[tt][jj] = __shfl_xor(accA[tt][2 + jj], 32);
                swB[tt][jj] = __shfl_xor(accB[tt][2 + jj], 32);
            }
        }

        // ---- EW: 2 rows per set per lane -> h into buf[(n+1)&1] ----
        if (valid && n < TT) {                 // set A: h0(n), col u
            #pragma unroll
            for (int jj = 0; jj < 2; ++jj) {
                const float pi = hi ? swA[0][jj] : accA[0][jj];
                const float pf = hi ? swA[1][jj] : accA[1][jj];
                const float pg = hi ? swA[2][jj] : accA[2][jj];
                const float po = hi ? swA[3][jj] : accA[3][jj];
                const float ei = fexp2(pi);
                const float ef = fexp2(pf);
                const float eg = fexp2(pg);
                const float eo = fexp2(po);
                const float ig = (eg - 1.0f) * frcp((eg + 1.0f) * (1.0f + ei));
                const float fv = frcp(1.0f + ef);
                const float c  = fv * cstA[jj] + ig;
                cstA[jj] = c;
                const float ec = fexp2(c * (2.0f * LOG2E));
                const float h  = (ec - 1.0f) * frcp((ec + 1.0f) * (1.0f + eo));
                s_A[(n + 1) & 1][rwb + jj][u] = f2h_bits(h);
            }
        }
        if (valid && n >= 1) {                 // set B: h1(n-1), col 64+u
            #pragma unroll
            for (int jj = 0; jj < 2; ++jj) {
                const float pi = hi ? swB[0][jj] : accB[0][jj];
                const float pf = hi ? swB[1][jj] : accB[1][jj];
                const float pg = hi ? swB[2][jj] : accB[2][jj];
                const float po = hi ? swB[3][jj] : accB[3][jj];
                const float ei = fexp2(pi);
                const float ef = fexp2(pf);
                const float eg = fexp2(pg);
                const float eo = fexp2(po);
                const float ig = (eg - 1.0f) * frcp((eg + 1.0f) * (1.0f + ei));
                const float fv = frcp(1.0f + ef);
                const float c  = fv * cstB[jj] + ig;
                cstB[jj] = c;
                const float ec = fexp2(c * (2.0f * LOG2E));
                const float h  = (ec - 1.0f) * frcp((ec + 1.0f) * (1.0f + eo));
                s_A[(n + 1) & 1][rwb + jj][64 + u] = f2h_bits(h);
            }
        }
        if (xduty && (n + 1) < TT) {           // x(n+1) -> buf[(n+1)&1]
            const int tn = n + 1;
            #pragma unroll
            for (int e = 0; e < 2; ++e) {
                const int slot = 2 * xi + e;
                const int rr = slot / 3, dd = slot % 3;
                s_A[(n + 1) & 1][rr][HD + dd] =
                    f2h_bits(s_xs[(tn / TC) & 1][rr][(tn % TC) * 3 + dd]);
            }
        }
        {
            const int t2s = n + 2;             // stage next x chunk 2 ticks ahead
            if (t2s < TT && (t2s % TC) == 0) {
                const int cb = (t2s / TC) & 1;
                for (int q = tid; q < BRR * TC * 3; q += 256) {
                    const int rr = q / (TC * 3), qq = q % (TC * 3);
                    s_xs[cb][rr][qq] = x[(size_t)(r0 + rr) * (TT * 3) + (size_t)t2s * 3 + qq];
                }
            }
        }
        __syncthreads();
    }

    // ---- FC epilogue: h1(TT-1) in buf[(TT+1)&1] = buf1, cols 64..113 ----
    if (tid < BRR * 7) {
        const int r = tid / 7, o = tid % 7;
        float acc = bfc[o];
        #pragma unroll
        for (int uu = 0; uu < HD; ++uu)
            acc += h2f(s_A[1][r][64 + uu]) * Wfc[o * HD + uu];
        out[(size_t)(r0 + r) * 7 + o] = acc;
    }
}

extern "C" void kernel_launch(void* const* d_in, const int* in_sizes, int n_in,
                              void* d_out, int out_size, void* d_ws, size_t ws_size,
                              hipStream_t stream) {
    const float* xp    = (const float*)d_in[0];
    const float* Wih0  = (const float*)d_in[1];
    const float* Whh0  = (const float*)d_in[2];
    const float* bih0  = (const float*)d_in[3];
    const float* bhh0  = (const float*)d_in[4];
    const float* Wih1  = (const float*)d_in[5];
    const float* Whh1  = (const float*)d_in[6];
    const float* bih1  = (const float*)d_in[7];
    const float* bhh1  = (const float*)d_in[8];
    const float* Wfc   = (const float*)d_in[9];
    const float* bfc   = (const float*)d_in[10];
    float* outp = (float*)d_out;

    const int B = in_sizes[0] / (TT * 3);   // 4096
    const int grid = B / BRR;               // 512 blocks -> 2 per CU

    lstm2_dual<<<grid, 256, 0, stream>>>(
        xp, Wih0, Whh0, bih0, bhh0, Wih1, Whh1, bih1, bhh1, Wfc, bfc, outp);
}

// Round 16
// 385.770 us; speedup vs baseline: 1.4963x; 1.4963x over previous
//
#include <hip/hip_runtime.h>

#define HD 50
#define TT 512
#define BRR 16        // batch rows per block -> 256 blocks = 1/CU
#define TC 32         // x prefetch chunk (timesteps)
#define KS 136        // shorts per A row (272B): [0..49]=h0 | [50..52]=x | 53..63=0 | [64..113]=h1 | 114..135=0

using f16   = _Float16;
using f16x8 = __attribute__((ext_vector_type(8))) f16;
using f32x4 = __attribute__((ext_vector_type(4))) float;

#define LOG2E 1.4426950408889634f

__device__ __forceinline__ short f2h_bits(float f) {
    f16 h = (f16)f;                      // RNE
    return *reinterpret_cast<short*>(&h);
}
__device__ __forceinline__ float h2f(short b) {
    f16 h = *reinterpret_cast<f16*>(&b);
    return (float)h;
}
__device__ __forceinline__ float frcp(float x) { return __builtin_amdgcn_rcpf(x); }
#if __has_builtin(__builtin_amdgcn_exp2f)
__device__ __forceinline__ float fexp2(float x) { return __builtin_amdgcn_exp2f(x); }
#else
__device__ __forceinline__ float fexp2(float x) { return exp2f(x); }
#endif

// r13 champion structure (unified one-barrier tick) + paired-rcp EW + unroll 2.
// A(n) = [h0(n-1) | x(n) | h1(n-2)] (k=128); one MFMA pass computes L0(n) and
// L1(n-1) gates. Wave w owns (layer,unit) pairs p = 8*lr + w. EW in-register;
// A double-buffered. Weights pre-scaled by -log2e / +2log2e.
// EW trans budget: 5 exp2 + 1 rcp per j, rcp's shared pairwise across j
// (r=rcp(a*b); 1/a=r*b) -> 24 trans instrs/lane (was 32).
__global__ __launch_bounds__(512, 2) void lstm2_uni3(
    const float* __restrict__ x,
    const float* __restrict__ Wih0, const float* __restrict__ Whh0,
    const float* __restrict__ bih0, const float* __restrict__ bhh0,
    const float* __restrict__ Wih1, const float* __restrict__ Whh1,
    const float* __restrict__ bih1, const float* __restrict__ bhh1,
    const float* __restrict__ Wfc, const float* __restrict__ bfc,
    float* __restrict__ out)
{
    __shared__ short s_A[2][BRR][KS];
    __shared__ float s_xs[2][BRR][TC * 3];

    const int tid  = threadIdx.x;
    const int wid  = tid >> 6;
    const int lane = tid & 63;
    const int lr   = lane & 15;          // B/D column = pair slot
    const int lq   = lane >> 4;          // k-octet / D row-quad
    const int r0   = blockIdx.x * BRR;

    const int  p     = 8 * lr + wid;     // pair id 0..127
    const bool valid = (p < 100);
    const bool isL1  = valid && (p >= 50);
    const int  u     = valid ? (isL1 ? p - 50 : p) : 0;
    const int  wcol  = isL1 ? 64 + u : u;        // h write column in A

    // ---- weight B-fragments (f16, pre-scaled), register-resident ----
    f16x8 bw[4][4];
    float bvT[4];
    #pragma unroll
    for (int tt = 0; tt < 4; ++tt) {
        const float sc = (tt == 2) ? (2.0f * LOG2E) : (-LOG2E);
        const int g = tt * HD + u;       // layer-local gate row
        if (!isL1) {
            bvT[tt] = valid ? (bih0[g] + bhh0[g]) * sc : 0.f;
            #pragma unroll
            for (int s = 0; s < 4; ++s) {
                #pragma unroll
                for (int j = 0; j < 8; ++j) {
                    const int k = s*32 + lq*8 + j;
                    float wv = 0.f;
                    if (valid) {
                        if (k < HD) wv = Whh0[g*HD + k];
                        else if (k < HD + 3) wv = Wih0[g*3 + (k - HD)];
                    }
                    bw[tt][s][j] = (f16)(wv * sc);
                }
            }
        } else {
            bvT[tt] = (bih1[g] + bhh1[g]) * sc;
            #pragma unroll
            for (int s = 0; s < 4; ++s) {
                #pragma unroll
                for (int j = 0; j < 8; ++j) {
                    const int k = s*32 + lq*8 + j;
                    float wv = 0.f;
                    if (k < HD) wv = Wih1[g*HD + k];
                    else if (k >= 64 && k < 64 + HD) wv = Whh1[g*HD + (k - 64)];
                    bw[tt][s][j] = (f16)(wv * sc);
                }
            }
        }
    }

    // ---- per-lane c-state: 4 batch rows (4*lq+j) of this lane's (layer,unit) ----
    float cst[4] = {0.f, 0.f, 0.f, 0.f};

    // ---- x duty: the 48 invalid lanes of waves 0-3 (lr>=13 -> p>=104) ----
    const bool xduty = (wid < 4) && (lr >= 13);
    const int  xidx  = wid * 12 + (lr - 13) * 4 + lq;   // 0..47
    const int  xrow  = xidx / 3, xd = xidx % 3;

    // ---- init: zero A buffers, stage x chunk 0, write x(0) ----
    for (int q = tid; q < 2 * BRR * KS; q += 512) ((short*)s_A)[q] = 0;
    for (int q = tid; q < BRR * TC * 3; q += 512) {
        const int rr = q / (TC * 3), qq = q % (TC * 3);
        s_xs[0][rr][qq] = x[(size_t)(r0 + rr) * (TT * 3) + qq];
    }
    __syncthreads();
    if (xduty) s_A[0][xrow][HD + xd] = f2h_bits(s_xs[0][xrow][xd]);
    __syncthreads();

    // ================= main loop: TT+1 ticks, ONE barrier each =================
    #pragma unroll 2
    for (int n = 0; n <= TT; ++n) {
        // ---- MFMA: gates for L0(n) and L1(n-1) in one pass ----
        const char* ab = (const char*)&s_A[n & 1][0][0];
        f16x8 a[4];
        #pragma unroll
        for (int s = 0; s < 4; ++s)
            a[s] = *(const f16x8*)(ab + lr * (2 * KS) + s * 64 + lq * 16);
        f32x4 acc[4];
        #pragma unroll
        for (int tt = 0; tt < 4; ++tt) { const float b = bvT[tt]; acc[tt] = (f32x4){b, b, b, b}; }
        #pragma unroll
        for (int s = 0; s < 4; ++s) {
            #pragma unroll
            for (int tt = 0; tt < 4; ++tt)
                acc[tt] = __builtin_amdgcn_mfma_f32_16x16x32_f16(a[s], bw[tt][s], acc[tt], 0, 0, 0);
        }

        // ---- EW in-register (paired rcp) -> h into buf[(n+1)&1] ----
        const bool act = valid && (isL1 ? (n >= 1) : (n < TT));
        if (act) {
            // pass 1: form stage-1 denominator products P[j] = D1*D2
            float P[4], num1[4], D1[4], D2[4], eo4[4];
            #pragma unroll
            for (int j = 0; j < 4; ++j) {
                const float ei = fexp2(acc[0][j]);
                const float ef = fexp2(acc[1][j]);
                const float eg = fexp2(acc[2][j]);
                eo4[j] = fexp2(acc[3][j]);
                D1[j] = (eg + 1.0f) * (1.0f + ei);
                D2[j] = 1.0f + ef;
                P[j]  = D1[j] * D2[j];
                num1[j] = eg - 1.0f;
            }
            // shared rcp across j-pairs for stage 1
            const float rA = frcp(P[0] * P[1]);
            const float rB = frcp(P[2] * P[3]);
            const float iP[4] = { rA * P[1], rA * P[0], rB * P[3], rB * P[2] };
            // c update + stage-2 denominators
            float num2[4], den2[4];
            #pragma unroll
            for (int j = 0; j < 4; ++j) {
                const float ig = num1[j] * (iP[j] * D2[j]);   // tanh(g)*sig(i)
                const float fv = iP[j] * D1[j];               // sig(f)
                const float c  = fv * cst[j] + ig;
                cst[j] = c;
                const float ec = fexp2(c * (2.0f * LOG2E));
                num2[j] = ec - 1.0f;
                den2[j] = (ec + 1.0f) * (1.0f + eo4[j]);
            }
            // shared rcp across j-pairs for stage 2, write h
            const float rC = frcp(den2[0] * den2[1]);
            const float rD = frcp(den2[2] * den2[3]);
            const float iD[4] = { rC * den2[1], rC * den2[0], rD * den2[3], rD * den2[2] };
            #pragma unroll
            for (int j = 0; j < 4; ++j)
                s_A[(n + 1) & 1][lq * 4 + j][wcol] = f2h_bits(num2[j] * iD[j]);
        }
        if (xduty && (n + 1) < TT) {                  // x(n+1) from staged LDS
            const int tn = n + 1;
            s_A[(n + 1) & 1][xrow][HD + xd] =
                f2h_bits(s_xs[(tn / TC) & 1][xrow][(tn % TC) * 3 + xd]);
        }
        {
            const int t2s = n + 2;                    // stage next x chunk 2 ticks ahead
            if (t2s < TT && (t2s % TC) == 0) {
                const int cb = (t2s / TC) & 1;
                for (int q = tid; q < BRR * TC * 3; q += 512) {
                    const int rr = q / (TC * 3), qq = q % (TC * 3);
                    s_xs[cb][rr][qq] = x[(size_t)(r0 + rr) * (TT * 3) + (size_t)t2s * 3 + qq];
                }
            }
        }
        __syncthreads();
    }

    // ---- FC epilogue: h1(TT-1) sits in buf[(TT+1)&1] = buf[1], cols 64..113 ----
    if (tid < BRR * 7) {
        const int r = tid / 7, o = tid % 7;
        float acc = bfc[o];
        #pragma unroll
        for (int uu = 0; uu < HD; ++uu)
            acc += h2f(s_A[1][r][64 + uu]) * Wfc[o * HD + uu];
        out[(size_t)(r0 + r) * 7 + o] = acc;
    }
}

extern "C" void kernel_launch(void* const* d_in, const int* in_sizes, int n_in,
                              void* d_out, int out_size, void* d_ws, size_t ws_size,
                              hipStream_t stream) {
    const float* xp    = (const float*)d_in[0];
    const float* Wih0  = (const float*)d_in[1];
    const float* Whh0  = (const float*)d_in[2];
    const float* bih0  = (const float*)d_in[3];
    const float* bhh0  = (const float*)d_in[4];
    const float* Wih1  = (const float*)d_in[5];
    const float* Whh1  = (const float*)d_in[6];
    const float* bih1  = (const float*)d_in[7];
    const float* bhh1  = (const float*)d_in[8];
    const float* Wfc   = (const float*)d_in[9];
    const float* bfc   = (const float*)d_in[10];
    float* outp = (float*)d_out;

    const int B = in_sizes[0] / (TT * 3);   // 4096
    const int grid = B / BRR;               // 256 blocks, 1 per CU

    lstm2_uni3<<<grid, 512, 0, stream>>>(
        xp, Wih0, Whh0, bih0, bhh0, Wih1, Whh1, bih1, bhh1, Wfc, bfc, outp);
}